// Round 1
// baseline (2752.180 us; speedup 1.0000x reference)
//
#include <hip/hip_runtime.h>

// ---------------------------------------------------------------------------
// GenesisV1: embed -> 256-step gated node recurrence -> LN -> vocab logits
//
// Key decomposition: combined@W = x_t@W_top (precomputed, batched) +
// nodes@W_bot (recurrent). Each (batch,node) chain is independent ->
// 512 chains -> 32 workgroups of 16 chains each, no inter-WG communication.
// All GEMMs use mfma_f32_16x16x32_bf16 with pre-packed fragment layouts:
//   A-frag: lane l holds A[m = l&15][k = (l>>4)*8 + j], j=0..7   (16B/lane)
//   B-frag: lane l holds B[k = (l>>4)*8 + j][n = l&15]
//   D:      lane l holds D[row = (l>>4)*4 + r][col = l&15]
// ---------------------------------------------------------------------------

#define NBATCH 8
#define SEQ    256
#define DM     512
#define VOCAB  32000
#define NNODES 64
#define MROWS  2048   // NBATCH*SEQ
#define KT     16     // DM/32 k-tiles

typedef __attribute__((ext_vector_type(8))) short s8v;  // 8 bf16 in 4 VGPRs
typedef __attribute__((ext_vector_type(4))) float f4v;

// ---- workspace layout (bytes) ----
#define OFF_XFRAG  0u                    // [128 mt][16 kt][64][8] bf16 : 2 MB
#define OFF_BPKTOP 2097152u              // [64 nt][16 kt][64][8] bf16 : 1 MB
#define OFF_BPKREC 3145728u              // same                       : 1 MB
#define OFF_WHPK   4194304u              // [2000 nt][16][64][8] bf16  : 32.77 MB
#define OFF_XGU    36962304u             // [2048][1024] f32           : 8 MB
#define OFF_PART   45350912u             // [8][4][256][512] f32       : 16.78 MB
#define OFF_NORM   62128128u             // [128 mt][16][64][8] bf16   : 2 MB
// total ~61.3 MB

__device__ __forceinline__ short f2bf(float f) {
  unsigned u = __builtin_bit_cast(unsigned, f);
  u += 0x7fffu + ((u >> 16) & 1u);          // round-to-nearest-even
  return (short)(u >> 16);
}
__device__ __forceinline__ float fsig(float x) {
  float e = __builtin_amdgcn_exp2f(-1.4426950408889634f * x);
  return __builtin_amdgcn_rcpf(1.0f + e);
}
__device__ __forceinline__ float ftanh(float x) {
  float xc = fminf(fmaxf(x, -15.0f), 15.0f); // avoid inf/inf -> NaN
  float e = __builtin_amdgcn_exp2f(2.8853900817779268f * xc); // e^(2x)
  return (e - 1.0f) * __builtin_amdgcn_rcpf(e + 1.0f);
}

// ---- pack Wg/Wu (both [1024,512] f32) into top (x-part) and bottom (node-
// part) B-fragment tensors. nt 0..31 = gate cols, nt 32..63 = cand cols. ----
__global__ __launch_bounds__(256) void k_packw(const float* __restrict__ Wg,
                                               const float* __restrict__ Wu,
                                               short* __restrict__ top,
                                               short* __restrict__ rec) {
  int t = blockIdx.x * 256 + threadIdx.x;   // 131072 total
  int l = t & 63, kt = (t >> 6) & 15, nt = (t >> 10) & 31;
  int ub = (t >> 15) & 1, tb = (t >> 16) & 1;
  const float* src = ub ? Wu : Wg;
  int row0 = tb * 512 + kt * 32 + ((l >> 4) << 3);
  int col  = nt * 16 + (l & 15);
  short* dst = tb ? rec : top;
  int base = (((ub * 32 + nt) * KT + kt) * 64 + l) * 8;
#pragma unroll
  for (int j = 0; j < 8; ++j) dst[base + j] = f2bf(src[(row0 + j) * 512 + col]);
}

// ---- pack Wh [512,32000] f32 -> bf16 B-fragments ----
__global__ __launch_bounds__(256) void k_packwh(const float* __restrict__ Wh,
                                                short* __restrict__ whpk) {
  int t = blockIdx.x * 256 + threadIdx.x;   // 2,048,000 total
  int l = t & 63, kt = (t >> 6) & 15, nt = t >> 10;  // nt 0..1999
  int row0 = kt * 32 + ((l >> 4) << 3);
  int col  = nt * 16 + (l & 15);
  int base = ((nt * KT + kt) * 64 + l) * 8;
#pragma unroll
  for (int j = 0; j < 8; ++j) whpk[base + j] = f2bf(Wh[(row0 + j) * VOCAB + col]);
}

// ---- gather x = embedding[idx] -> bf16 A-fragments ----
__global__ __launch_bounds__(256) void k_gather(const int* __restrict__ idx,
                                                const float* __restrict__ emb,
                                                short* __restrict__ xfrag) {
  int t = blockIdx.x * 256 + threadIdx.x;   // 131072 total
  int l = t & 63, kt = (t >> 6) & 15, mt = t >> 10;  // mt 0..127
  int m = mt * 16 + (l & 15);
  int tok = idx[m];
  const float* e = emb + (long)tok * DM + kt * 32 + ((l >> 4) << 3);
  int base = ((mt * KT + kt) * 64 + l) * 8;
#pragma unroll
  for (int j = 0; j < 8; ++j) xfrag[base + j] = f2bf(e[j]);
}

// ---- Xgu = x @ [Wg_top|Wu_top] + [bg|bu] : [2048][1024] f32 ----
__global__ __launch_bounds__(256) void k_xgemm(const short* __restrict__ xfrag,
                                               const short* __restrict__ bpk,
                                               const float* __restrict__ bg,
                                               const float* __restrict__ bu,
                                               float* __restrict__ xgu) {
  int tid = threadIdx.x, l = tid & 63, w = tid >> 6;
  int mtb = blockIdx.x;            // 0..31 (4 mt each)
  int nt  = blockIdx.y * 4 + w;    // 0..63
  f4v acc[4];
#pragma unroll
  for (int mi = 0; mi < 4; ++mi) acc[mi] = 0;
  for (int kt = 0; kt < KT; ++kt) {
    s8v bf = *(const s8v*)(bpk + ((nt * KT + kt) * 64 + l) * 8);
#pragma unroll
    for (int mi = 0; mi < 4; ++mi) {
      s8v a = *(const s8v*)(xfrag + (((mtb * 4 + mi) * KT + kt) * 64 + l) * 8);
      acc[mi] = __builtin_amdgcn_mfma_f32_16x16x32_bf16(a, bf, acc[mi], 0, 0, 0);
    }
  }
  int n = nt * 16 + (l & 15);
  float bias = (n < 512) ? bg[n] : bu[n - 512];
#pragma unroll
  for (int mi = 0; mi < 4; ++mi)
#pragma unroll
    for (int r = 0; r < 4; ++r) {
      int m = (mtb * 4 + mi) * 16 + ((l >> 4) << 2) + r;
      xgu[m * 1024 + n] = acc[mi][r] + bias;
    }
}

// ---- the recurrence: 32 WGs x 512 threads; WG = (batch, 16-node block).
// 8 waves; wave v owns h-columns [64v, 64v+64) = k-tiles {2v,2v+1}.
// h: f32 master in regs, bf16 A-frags in LDS (double-buffered, 1 barrier/step).
__global__ __launch_bounds__(512) void k_recur(const short* __restrict__ bpk,
                                               const float* __restrict__ xgu,
                                               const float* __restrict__ mn,
                                               float* __restrict__ part) {
  __shared__ short hfrag[2][KT * 64 * 8];   // 2 x 16 KB
  const int tid = threadIdx.x;
  const int l = tid & 63, v = tid >> 6;     // wave 0..7
  const int bat = blockIdx.x >> 2, nb = blockIdx.x & 3;
  const int lm = l & 15, lq = l >> 4;

  // init h from manifold_nodes
  float hm[4][4];
#pragma unroll
  for (int s = 0; s < 4; ++s) {
    int col = 64 * v + 16 * s + lm;
#pragma unroll
    for (int r = 0; r < 4; ++r) {
      int node = nb * 16 + lq * 4 + r;
      float h0 = mn[node * DM + col];
      hm[s][r] = h0;
      int kk = 16 * (s & 1) + lm;
      int ldst = (lq * 4 + r) + ((kk >> 3) << 4);
      hfrag[0][((2 * v + (s >> 1)) * 64 + ldst) * 8 + (l & 7)] = f2bf(h0);
    }
  }
  __syncthreads();

  for (int t = 0; t < SEQ; ++t) {
    const int cur = t & 1, nxt = cur ^ 1;
    // prefetch the per-timestep x-part pre-activations
    float xg[4], xu[4];
    const float* xrow = xgu + (bat * SEQ + t) * 1024;
#pragma unroll
    for (int s = 0; s < 4; ++s) {
      xg[s] = xrow[64 * v + 16 * s + lm];
      xu[s] = xrow[512 + 64 * v + 16 * s + lm];
    }
    f4v accg[4], accu[4];
#pragma unroll
    for (int s = 0; s < 4; ++s) { accg[s] = 0; accu[s] = 0; }
#pragma unroll 2
    for (int kt = 0; kt < KT; ++kt) {
      s8v a = *(const s8v*)(&hfrag[cur][(kt * 64 + l) * 8]);
#pragma unroll
      for (int s = 0; s < 4; ++s) {
        s8v bgf = *(const s8v*)(bpk + (((4 * v + s) * KT + kt) * 64 + l) * 8);
        s8v buf = *(const s8v*)(bpk + (((32 + 4 * v + s) * KT + kt) * 64 + l) * 8);
        accg[s] = __builtin_amdgcn_mfma_f32_16x16x32_bf16(a, bgf, accg[s], 0, 0, 0);
        accu[s] = __builtin_amdgcn_mfma_f32_16x16x32_bf16(a, buf, accu[s], 0, 0, 0);
      }
    }
    // epilogue: gate/cand/update, write next-step frags, consensus partials
    float ps[4];
#pragma unroll
    for (int s = 0; s < 4; ++s) {
      ps[s] = 0.0f;
#pragma unroll
      for (int r = 0; r < 4; ++r) {
        float g = fsig(accg[s][r] + xg[s]);
        float c = ftanh(accu[s][r] + xu[s]);
        float h = g * c + (1.0f - g) * hm[s][r];
        hm[s][r] = h;
        ps[s] += h;
        int kk = 16 * (s & 1) + lm;
        int ldst = (lq * 4 + r) + ((kk >> 3) << 4);
        hfrag[nxt][((2 * v + (s >> 1)) * 64 + ldst) * 8 + (l & 7)] = f2bf(h);
      }
      ps[s] += __shfl_xor(ps[s], 16);
      ps[s] += __shfl_xor(ps[s], 32);
    }
    if (l < 16) {
      float* pp = part + (((bat * 4 + nb) * SEQ + t) * DM) + 64 * v + l;
#pragma unroll
      for (int s = 0; s < 4; ++s) pp[16 * s] = ps[s];
    }
    __syncthreads();
  }
}

// ---- consensus = sum(partials)/64 -> LayerNorm -> bf16 A-fragments ----
__global__ __launch_bounds__(1024) void k_ln(const float* __restrict__ part,
                                             const float* __restrict__ lnw,
                                             const float* __restrict__ lnb,
                                             short* __restrict__ nfrag) {
  __shared__ short tile[16 * DM];           // 16 KB
  int tid = threadIdx.x, w = tid >> 6, l = tid & 63;
  int bI = blockIdx.x;                      // 0..127  (16 rows each)
  int m = bI * 16 + w;
  int bat = m >> 8, t = m & 255;
  const float* p0 = part + ((bat * 4) * SEQ + t) * DM;
  float vx[8];
#pragma unroll
  for (int j = 0; j < 8; ++j) {
    int d = l * 8 + j;
    vx[j] = (p0[d] + p0[d + 131072] + p0[d + 262144] + p0[d + 393216]) * (1.0f / 64.0f);
  }
  float s = 0;
#pragma unroll
  for (int j = 0; j < 8; ++j) s += vx[j];
  for (int msk = 1; msk < 64; msk <<= 1) s += __shfl_xor(s, msk);
  float mean = s * (1.0f / 512.0f);
  float q = 0;
#pragma unroll
  for (int j = 0; j < 8; ++j) { float d = vx[j] - mean; q += d * d; }
  for (int msk = 1; msk < 64; msk <<= 1) q += __shfl_xor(q, msk);
  float rs = rsqrtf(q * (1.0f / 512.0f) + 1e-5f);
#pragma unroll
  for (int j = 0; j < 8; ++j) {
    int d = l * 8 + j;
    tile[w * DM + d] = f2bf((vx[j] - mean) * rs * lnw[d] + lnb[d]);
  }
  __syncthreads();
  // re-emit in A-fragment order: thread tid -> (kt = w, lane l)
  s8v val = *(const s8v*)(&tile[(l & 15) * DM + w * 32 + ((l >> 4) << 3)]);
  *(s8v*)(nfrag + ((bI * KT + w) * 64 + l) * 8) = val;
}

// ---- logits = normed @ Wh + bh : [2048][32000] f32 out ----
__global__ __launch_bounds__(512) void k_logits(const short* __restrict__ nfrag,
                                                const short* __restrict__ whpk,
                                                const float* __restrict__ bh,
                                                float* __restrict__ out) {
  int tid = threadIdx.x, l = tid & 63, w = tid >> 6;  // 8 waves
  int wm = w >> 2, wn = w & 3;
  int ntb = blockIdx.x;   // 0..124 (256 cols each)
  int mtb = blockIdx.y;   // 0..7   (256 rows each)
  f4v acc[8][4];
#pragma unroll
  for (int mi = 0; mi < 8; ++mi)
#pragma unroll
    for (int ni = 0; ni < 4; ++ni) acc[mi][ni] = 0;
  for (int kt = 0; kt < KT; ++kt) {
    s8v bf[4];
#pragma unroll
    for (int ni = 0; ni < 4; ++ni)
      bf[ni] = *(const s8v*)(whpk + (((ntb * 16 + wn * 4 + ni) * KT + kt) * 64 + l) * 8);
#pragma unroll
    for (int mi = 0; mi < 8; ++mi) {
      s8v a = *(const s8v*)(nfrag + (((mtb * 16 + wm * 8 + mi) * KT + kt) * 64 + l) * 8);
#pragma unroll
      for (int ni = 0; ni < 4; ++ni)
        acc[mi][ni] = __builtin_amdgcn_mfma_f32_16x16x32_bf16(a, bf[ni], acc[mi][ni], 0, 0, 0);
    }
  }
#pragma unroll
  for (int ni = 0; ni < 4; ++ni) {
    int n = (ntb * 16 + wn * 4 + ni) * 16 + (l & 15);
    float bias = bh[n];
#pragma unroll
    for (int mi = 0; mi < 8; ++mi) {
      int mrow = (mtb * 16 + wm * 8 + mi) * 16 + ((l >> 4) << 2);
#pragma unroll
      for (int r = 0; r < 4; ++r)
        out[(long)(mrow + r) * VOCAB + n] = acc[mi][ni][r] + bias;
    }
  }
}

extern "C" void kernel_launch(void* const* d_in, const int* in_sizes, int n_in,
                              void* d_out, int out_size, void* d_ws, size_t ws_size,
                              hipStream_t stream) {
  (void)in_sizes; (void)n_in; (void)out_size; (void)ws_size;
  const int*   idx = (const int*)  d_in[0];
  const float* emb = (const float*)d_in[1];
  const float* mn  = (const float*)d_in[2];
  const float* Wg  = (const float*)d_in[3];
  const float* bg  = (const float*)d_in[4];
  const float* Wu  = (const float*)d_in[5];
  const float* bu  = (const float*)d_in[6];
  const float* lnw = (const float*)d_in[7];
  const float* lnb = (const float*)d_in[8];
  const float* Wh  = (const float*)d_in[9];
  const float* bh  = (const float*)d_in[10];
  float* out = (float*)d_out;
  char* ws = (char*)d_ws;
  short* xfrag  = (short*)(ws + OFF_XFRAG);
  short* bpktop = (short*)(ws + OFF_BPKTOP);
  short* bpkrec = (short*)(ws + OFF_BPKREC);
  short* whpk   = (short*)(ws + OFF_WHPK);
  float* xgu    = (float*)(ws + OFF_XGU);
  float* part   = (float*)(ws + OFF_PART);
  short* nfrag  = (short*)(ws + OFF_NORM);

  k_packw <<<dim3(512),      dim3(256),  0, stream>>>(Wg, Wu, bpktop, bpkrec);
  k_packwh<<<dim3(8000),     dim3(256),  0, stream>>>(Wh, whpk);
  k_gather<<<dim3(512),      dim3(256),  0, stream>>>(idx, emb, xfrag);
  k_xgemm <<<dim3(32, 16),   dim3(256),  0, stream>>>(xfrag, bpktop, bg, bu, xgu);
  k_recur <<<dim3(32),       dim3(512),  0, stream>>>(bpkrec, xgu, mn, part);
  k_ln    <<<dim3(128),      dim3(1024), 0, stream>>>(part, lnw, lnb, nfrag);
  k_logits<<<dim3(125, 8),   dim3(512),  0, stream>>>(nfrag, whpk, bh, out);
}